// Round 11
// baseline (155.896 us; speedup 1.0000x reference)
//
#include <hip/hip_runtime.h>
#include <math.h>

#define HIDDEN 128
#define SCALE 0.25f
#define NB_KV 1024   // blocks for fused K+V flavor
#define NB_Q  512    // blocks for Q flavor
#define NB_O  512    // blocks for output projection

typedef __attribute__((ext_vector_type(8))) short short8v;
typedef __attribute__((ext_vector_type(4))) float f32x4;

__device__ __forceinline__ unsigned short f2bf(float f) {
  const unsigned u = __float_as_uint(f);
  const unsigned r = u + 0x7fffu + ((u >> 16) & 1u);   // RNE
  return (unsigned short)(r >> 16);
}
__device__ __forceinline__ unsigned pack_bf2(float a, float b) {
  unsigned r;
  asm("v_cvt_pk_bf16_f32 %0, %1, %2" : "=v"(r) : "v"(a), "v"(b));
  return r;
}
__device__ __forceinline__ float bflo(unsigned u) { return __uint_as_float(u << 16); }
__device__ __forceinline__ float bfhi(unsigned u) { return __uint_as_float(u & 0xffff0000u); }

// blocks 0..31: fragment-ordered bf16 weights: chunk m*2048+(n*4+kk)*64+l ->
//   W_m[n*16+(l&15)][kk*32+(l>>4)*8 + 0..7].  blocks 32..: zero counts+done.
__global__ __launch_bounds__(256) void init_kernel(
    const float* __restrict__ W0, const float* __restrict__ W1,
    const float* __restrict__ W2, const float* __restrict__ W3,
    unsigned short* __restrict__ Wfrag, int* __restrict__ zero_base, int nzero4)
{
  if (blockIdx.x < 32) {
    const int chunk = blockIdx.x * 256 + threadIdx.x;
    const int m = chunk >> 11;
    const int rem = chunk & 2047;
    const int l = rem & 63;
    const int nkk = rem >> 6;
    const int n = nkk >> 2, kk = nkk & 3;
    const float* W = (m == 0) ? W0 : (m == 1) ? W1 : (m == 2) ? W2 : W3;
    const int row = n * 16 + (l & 15);
    const int k0 = kk * 32 + (l >> 4) * 8;
    const float4 v0 = *(const float4*)&W[row * 128 + k0];
    const float4 v1 = *(const float4*)&W[row * 128 + k0 + 4];
    uint4 o;
    o.x = (unsigned)f2bf(v0.x) | ((unsigned)f2bf(v0.y) << 16);
    o.y = (unsigned)f2bf(v0.z) | ((unsigned)f2bf(v0.w) << 16);
    o.z = (unsigned)f2bf(v1.x) | ((unsigned)f2bf(v1.y) << 16);
    o.w = (unsigned)f2bf(v1.z) | ((unsigned)f2bf(v1.w) << 16);
    *(uint4*)&Wfrag[(size_t)chunk * 8] = o;
  } else {
    const int idx4 = (blockIdx.x - 32) * 256 + threadIdx.x;
    if (idx4 < nzero4)
      *(int4*)&zero_base[idx4 * 4] = make_int4(0, 0, 0, 0);
  }
}

// Fused edge-count + QKV projection. Count blocks FIRST (overlap with GEMM).
// GEMM: zero LDS, zero barriers. Wave owns 64 output cols; its 16 W-fragments
// live in registers (loaded once from L2-hot Wfrag). X B-fragments loaded
// directly from global (lane l: X[row=base+(l&15)][kk*32+(l>>4)*8..+7]).
// KV block: waves {0,1}=K cols {0-63,64-127}, waves {2,3}=V ditto -- all four
// waves share the same 16 x_src rows (one HBM read, siblings L2-hit).
// Q block: waves {0,1} rows+0, waves {2,3} rows+16; cols (w&1)*64.
// D layout (R10-proven): lane l reg r -> out[row=base+(l&15)][col=cb*16+(l>>4)*4+r].
__global__ __launch_bounds__(256, 3) void qkv_count_kernel(
    const float* __restrict__ x_src, const float* __restrict__ x_dst,
    const unsigned short* __restrict__ Wfrag,
    const float* __restrict__ bq, const float* __restrict__ bk,
    const float* __restrict__ bv,
    unsigned short* __restrict__ qb, unsigned short* __restrict__ kvb,
    int Nsrc, int Ndst,
    const int* __restrict__ ei, int E, int* __restrict__ counts, int cblocks)
{
  const int t = threadIdx.x;
  int bid = blockIdx.x;

  if (bid < cblocks) {            // -------- edge counting --------
    const int e = (bid * 256 + t) * 4;
    if (e + 4 <= E) {
      const int4 d = *(const int4*)&ei[E + e];
      atomicAdd(&counts[d.x], 1);
      atomicAdd(&counts[d.y], 1);
      atomicAdd(&counts[d.z], 1);
      atomicAdd(&counts[d.w], 1);
    } else {
      for (int k = e; k < E; ++k) atomicAdd(&counts[ei[E + k]], 1);
    }
    return;
  }
  bid -= cblocks;

  const int l = t & 63, w = t >> 6;
  const int r16 = l & 15, g16 = l >> 4;

  int cb4, rowmul, rowoff, N, ntiles, stride, tile0, ostride, ooff;
  const float *X, *bias;
  const unsigned short* wb;
  unsigned short* outp;
  if (bid < NB_KV) {              // K+V fused flavor
    const int isV = w >> 1;
    cb4 = (w & 1) * 4;
    wb = Wfrag + (isV ? 32768 : 16384);
    bias = isV ? bv : bk;
    X = x_src; outp = kvb; ostride = 256; ooff = isV ? 128 : 0;
    N = Nsrc; rowmul = 16; rowoff = 0;
    ntiles = (Nsrc + 15) >> 4; stride = NB_KV; tile0 = bid;
  } else {                        // Q flavor
    cb4 = (w & 1) * 4;
    wb = Wfrag; bias = bq;
    X = x_dst; outp = qb; ostride = 128; ooff = 0;
    N = Ndst; rowmul = 32; rowoff = (w >> 1) * 16;
    ntiles = (Ndst + 31) >> 5; stride = NB_Q; tile0 = bid - NB_KV;
  }

  short8v wfr[4][4];              // wave's 64 cols x full K: 16 frags, 64 VGPR
  #pragma unroll
  for (int nb = 0; nb < 4; ++nb)
    #pragma unroll
    for (int kk = 0; kk < 4; ++kk)
      wfr[nb][kk] = ((const short8v*)wb)[((cb4 + nb) * 4 + kk) * 64 + l];
  float4 bb[4];
  #pragma unroll
  for (int nb = 0; nb < 4; ++nb)
    bb[nb] = *(const float4*)&bias[(cb4 + nb) * 16 + g16 * 4];

  for (int tile = tile0; tile < ntiles; tile += stride) {
    const int row = tile * rowmul + rowoff + r16;
    const bool valid = row < N;
    const float* xp = X + (size_t)row * 128 + g16 * 8;
    float4 xv[8];
    #pragma unroll
    for (int kk = 0; kk < 4; ++kk) {
      xv[2 * kk]     = valid ? *(const float4*)(xp + kk * 32)     : make_float4(0.f, 0.f, 0.f, 0.f);
      xv[2 * kk + 1] = valid ? *(const float4*)(xp + kk * 32 + 4) : make_float4(0.f, 0.f, 0.f, 0.f);
    }
    short8v a[4];
    #pragma unroll
    for (int kk = 0; kk < 4; ++kk) {
      uint4 u;
      u.x = pack_bf2(xv[2 * kk].x,     xv[2 * kk].y);
      u.y = pack_bf2(xv[2 * kk].z,     xv[2 * kk].w);
      u.z = pack_bf2(xv[2 * kk + 1].x, xv[2 * kk + 1].y);
      u.w = pack_bf2(xv[2 * kk + 1].z, xv[2 * kk + 1].w);
      a[kk] = *(short8v*)&u;
    }
    f32x4 acc[4];                 // C-in = bias (R8-proven trick)
    #pragma unroll
    for (int nb = 0; nb < 4; ++nb)
      acc[nb] = (f32x4){bb[nb].x, bb[nb].y, bb[nb].z, bb[nb].w};
    #pragma unroll
    for (int kk = 0; kk < 4; ++kk)
      #pragma unroll
      for (int nb = 0; nb < 4; ++nb)
        acc[nb] = __builtin_amdgcn_mfma_f32_16x16x32_bf16(wfr[nb][kk], a[kk], acc[nb], 0, 0, 0);
    if (valid) {
      unsigned short* orow = outp + (size_t)row * ostride + ooff;
      #pragma unroll
      for (int nb = 0; nb < 4; ++nb) {
        uint2 o;
        o.x = pack_bf2(acc[nb][0], acc[nb][1]);
        o.y = pack_bf2(acc[nb][2], acc[nb][3]);
        *(uint2*)&orow[(cb4 + nb) * 16 + g16 * 4] = o;
      }
    }
  }
}

// Output projection: identical zero-LDS structure; agg is bf16 so B-fragments
// load directly (uint4); f32 float4 epilogue (R10-proven store form).
__global__ __launch_bounds__(256, 3) void out_gemm_kernel(
    const unsigned short* __restrict__ agg, const unsigned short* __restrict__ Wfrag_o,
    const float* __restrict__ bo, float* __restrict__ Y, int N)
{
  const int t = threadIdx.x;
  const int l = t & 63, w = t >> 6;
  const int r16 = l & 15, g16 = l >> 4;
  const int cb4 = (w & 1) * 4;
  const int rowoff = (w >> 1) * 16;
  const int ntiles = (N + 31) >> 5;

  short8v wfr[4][4];
  #pragma unroll
  for (int nb = 0; nb < 4; ++nb)
    #pragma unroll
    for (int kk = 0; kk < 4; ++kk)
      wfr[nb][kk] = ((const short8v*)Wfrag_o)[((cb4 + nb) * 4 + kk) * 64 + l];
  float4 bb[4];
  #pragma unroll
  for (int nb = 0; nb < 4; ++nb)
    bb[nb] = *(const float4*)&bo[(cb4 + nb) * 16 + g16 * 4];

  for (int tile = blockIdx.x; tile < ntiles; tile += NB_O) {
    const int row = tile * 32 + rowoff + r16;
    const bool valid = row < N;
    const unsigned short* ap = agg + (size_t)row * 128 + g16 * 8;
    uint4 av[4];
    #pragma unroll
    for (int kk = 0; kk < 4; ++kk)
      av[kk] = valid ? *(const uint4*)(ap + kk * 32) : make_uint4(0, 0, 0, 0);
    f32x4 acc[4];
    #pragma unroll
    for (int nb = 0; nb < 4; ++nb)
      acc[nb] = (f32x4){bb[nb].x, bb[nb].y, bb[nb].z, bb[nb].w};
    #pragma unroll
    for (int kk = 0; kk < 4; ++kk) {
      const short8v a = *(const short8v*)&av[kk];
      #pragma unroll
      for (int nb = 0; nb < 4; ++nb)
        acc[nb] = __builtin_amdgcn_mfma_f32_16x16x32_bf16(wfr[nb][kk], a, acc[nb], 0, 0, 0);
    }
    if (valid) {
      float* yrow = Y + (size_t)row * 128;
      #pragma unroll
      for (int nb = 0; nb < 4; ++nb)
        *(float4*)&yrow[(cb4 + nb) * 16 + g16 * 4] =
            make_float4(acc[nb][0], acc[nb][1], acc[nb][2], acc[nb][3]);
    }
  }
}

// Fused 3-phase scan (all blocks co-resident): block sums -> device-scope wait ->
// cross-block prefix + chunk exclusive scan.
__global__ __launch_bounds__(256) void scan_fused_kernel(
    const int* __restrict__ counts, int n, int* __restrict__ bsums,
    int* __restrict__ done, int* __restrict__ offsets)
{
  const int b = blockIdx.x, t = threadIdx.x;
  const int lane = t & 63, wid = t >> 6;
  const int idx = b * 256 + t;
  const int x = (idx < n) ? counts[idx] : 0;
  int v = x;
  #pragma unroll
  for (int off = 1; off < 64; off <<= 1) {
    const int tmp = __shfl_up(v, off);
    if (lane >= off) v += tmp;
  }
  __shared__ int wsum[4];
  __shared__ int base_s;
  if (lane == 63) wsum[wid] = v;
  __syncthreads();
  if (t == 0) {
    bsums[b] = wsum[0] + wsum[1] + wsum[2] + wsum[3];
    __threadfence();
    atomicAdd(done, 1);
    while (atomicAdd(done, 0) < (int)gridDim.x) {}
  }
  __syncthreads();
  __threadfence();
  int pre = (t < b) ? bsums[t] : 0;
  #pragma unroll
  for (int off = 1; off < 64; off <<= 1) pre += __shfl_xor(pre, off);
  __shared__ int pres[4];
  if (lane == 0) pres[wid] = pre;
  __syncthreads();
  if (t == 0) base_s = pres[0] + pres[1] + pres[2] + pres[3];
  __syncthreads();
  int wbase = 0;
  for (int p = 0; p < wid; ++p) wbase += wsum[p];
  if (idx < n) offsets[idx] = base_s + wbase + v - x;
}

// Destructive scatter: atomicAdd(&offsets[d],1) returns the absolute slot.
// Afterwards offsets[d] = start[d+1].
__global__ __launch_bounds__(256) void scatter_kernel(
    const int* __restrict__ ei, int E, int* __restrict__ offsets,
    int* __restrict__ csr_src)
{
  const int e = (blockIdx.x * 256 + threadIdx.x) * 4;
  if (e + 4 <= E) {
    const int4 s = *(const int4*)&ei[e];
    const int4 d = *(const int4*)&ei[E + e];
    int p;
    p = atomicAdd(&offsets[d.x], 1); csr_src[p] = s.x;
    p = atomicAdd(&offsets[d.y], 1); csr_src[p] = s.y;
    p = atomicAdd(&offsets[d.z], 1); csr_src[p] = s.z;
    p = atomicAdd(&offsets[d.w], 1); csr_src[p] = s.w;
  } else {
    for (int k = e; k < E; ++k) {
      const int d = ei[E + k];
      const int p = atomicAdd(&offsets[d], 1);
      csr_src[p] = ei[k];
    }
  }
}

// One wave per destination; lane=(eg=lane>>3, h=lane&7): full 16-dim dot per
// (edge,head). Row start = offsets[wave-1] (post-scatter), 0 for wave 0.
// End: butterfly reduce-scatter -> all-lane coalesced store.
__global__ __launch_bounds__(256) void edge_attn_kernel(
    const unsigned short* __restrict__ qb, const unsigned short* __restrict__ kvb,
    const float* __restrict__ eb, const int* __restrict__ offsets,
    const int* __restrict__ counts, const int* __restrict__ csr_src,
    unsigned short* __restrict__ agg, int Ndst)
{
  const int wave = blockIdx.x * 4 + (threadIdx.x >> 6);
  if (wave >= Ndst) return;
  const int lane = threadIdx.x & 63;
  const int eg = lane >> 3, h = lane & 7;

  const uint4 q0 = *(const uint4*)&qb[(size_t)wave * 128 + h * 16];
  const uint4 q1 = *(const uint4*)&qb[(size_t)wave * 128 + h * 16 + 8];
  const float bias = eb[h];
  const int ro = (wave == 0) ? 0 : offsets[wave - 1];
  const int cnt = counts[wave];

  float acc[16];
  #pragma unroll
  for (int j = 0; j < 16; ++j) acc[j] = 0.f;
  float s = 0.f;

  int e = eg;
  bool act = e < cnt;
  int src = act ? csr_src[ro + e] : 0;
  const int iters = (cnt + 7) >> 3;
  for (int it = 0; it < iters; ++it) {
    const size_t base = (size_t)src * 256 + h * 16;
    const uint4 k0 = *(const uint4*)&kvb[base];
    const uint4 k1 = *(const uint4*)&kvb[base + 8];
    const uint4 v0 = *(const uint4*)&kvb[base + 128];
    const uint4 v1 = *(const uint4*)&kvb[base + 136];
    const int e2 = e + 8;
    const bool act2 = e2 < cnt;
    const int src2 = act2 ? csr_src[ro + e2] : 0;

    float p = 0.f;
    p = fmaf(bflo(q0.x), bflo(k0.x), p); p = fmaf(bfhi(q0.x), bfhi(k0.x), p);
    p = fmaf(bflo(q0.y), bflo(k0.y), p); p = fmaf(bfhi(q0.y), bfhi(k0.y), p);
    p = fmaf(bflo(q0.z), bflo(k0.z), p); p = fmaf(bfhi(q0.z), bfhi(k0.z), p);
    p = fmaf(bflo(q0.w), bflo(k0.w), p); p = fmaf(bfhi(q0.w), bfhi(k0.w), p);
    p = fmaf(bflo(q1.x), bflo(k1.x), p); p = fmaf(bfhi(q1.x), bfhi(k1.x), p);
    p = fmaf(bflo(q1.y), bflo(k1.y), p); p = fmaf(bfhi(q1.y), bfhi(k1.y), p);
    p = fmaf(bflo(q1.z), bflo(k1.z), p); p = fmaf(bfhi(q1.z), bfhi(k1.z), p);
    p = fmaf(bflo(q1.w), bflo(k1.w), p); p = fmaf(bfhi(q1.w), bfhi(k1.w), p);

    const float wgt = act ? __expf(fmaf(p, SCALE, bias)) : 0.f;
    s += wgt;
    acc[0]  = fmaf(wgt, bflo(v0.x), acc[0]);  acc[1]  = fmaf(wgt, bfhi(v0.x), acc[1]);
    acc[2]  = fmaf(wgt, bflo(v0.y), acc[2]);  acc[3]  = fmaf(wgt, bfhi(v0.y), acc[3]);
    acc[4]  = fmaf(wgt, bflo(v0.z), acc[4]);  acc[5]  = fmaf(wgt, bfhi(v0.z), acc[5]);
    acc[6]  = fmaf(wgt, bflo(v0.w), acc[6]);  acc[7]  = fmaf(wgt, bfhi(v0.w), acc[7]);
    acc[8]  = fmaf(wgt, bflo(v1.x), acc[8]);  acc[9]  = fmaf(wgt, bfhi(v1.x), acc[9]);
    acc[10] = fmaf(wgt, bflo(v1.y), acc[10]); acc[11] = fmaf(wgt, bfhi(v1.y), acc[11]);
    acc[12] = fmaf(wgt, bflo(v1.z), acc[12]); acc[13] = fmaf(wgt, bfhi(v1.z), acc[13]);
    acc[14] = fmaf(wgt, bflo(v1.w), acc[14]); acc[15] = fmaf(wgt, bfhi(v1.w), acc[15]);
    e = e2; act = act2; src = src2;
  }

  // reduce-scatter butterfly over eg (lanes ^8, ^16, ^32) -- R8-proven pairing
  const bool b0 = eg & 1, b1 = (eg >> 1) & 1, b2 = (eg >> 2) & 1;
  float r8[8];
  #pragma unroll
  for (int j = 0; j < 8; ++j) {
    const float keep = b0 ? acc[j + 8] : acc[j];
    const float send = b0 ? acc[j] : acc[j + 8];
    r8[j] = keep + __shfl_xor(send, 8);
  }
  float r4[4];
  #pragma unroll
  for (int j = 0; j < 4; ++j) {
    const float keep = b1 ? r8[j + 4] : r8[j];
    const float send = b1 ? r8[j] : r8[j + 4];
    r4[j] = keep + __shfl_xor(send, 16);
  }
  float r2[2];
  #pragma unroll
  for (int j = 0; j < 2; ++j) {
    const float keep = b2 ? r4[j + 2] : r4[j];
    const float send = b2 ? r4[j] : r4[j + 2];
    r2[j] = keep + __shfl_xor(send, 32);
  }
  s += __shfl_xor(s, 8); s += __shfl_xor(s, 16); s += __shfl_xor(s, 32);
  const float rs = 1.0f / (s + 1e-8f);
  const int col = h * 16 + (b0 ? 8 : 0) + (b1 ? 4 : 0) + (b2 ? 2 : 0);
  *(unsigned*)&agg[(size_t)wave * 128 + col] = pack_bf2(r2[0] * rs, r2[1] * rs);
}

extern "C" void kernel_launch(void* const* d_in, const int* in_sizes, int n_in,
                              void* d_out, int out_size, void* d_ws, size_t ws_size,
                              hipStream_t stream) {
  const float* x_src = (const float*)d_in[0];
  const float* x_dst = (const float*)d_in[1];
  const int*   ei    = (const int*)d_in[2];
  const float* Wq = (const float*)d_in[3];
  const float* bq = (const float*)d_in[4];
  const float* Wk = (const float*)d_in[5];
  const float* bk = (const float*)d_in[6];
  const float* Wv = (const float*)d_in[7];
  const float* bv = (const float*)d_in[8];
  const float* Wo = (const float*)d_in[9];
  const float* bo = (const float*)d_in[10];
  const float* eb = (const float*)d_in[11];

  const int Nsrc = in_sizes[0] / HIDDEN;
  const int Ndst = in_sizes[1] / HIDDEN;
  const int E    = in_sizes[2] / 2;

  char* w = (char*)d_ws;
  unsigned short* qb   = (unsigned short*)w; w += (size_t)Ndst * 128 * 2;
  unsigned short* kvb  = (unsigned short*)w; w += (size_t)Nsrc * 256 * 2;
  unsigned short* aggb = (unsigned short*)w; w += (size_t)Ndst * 128 * 2;
  unsigned short* Wb   = (unsigned short*)w; w += (size_t)4 * 16384 * 2;
  int* counts  = (int*)w; w += (size_t)Ndst * sizeof(int);        // zero region start
  int* done    = (int*)w; w += 64 * sizeof(int);                  // contiguous w/ counts
  int* offsets = (int*)w; w += (size_t)Ndst * sizeof(int);
  int* bsums   = (int*)w; w += 256 * sizeof(int);
  int* csr_src = (int*)w; w += (size_t)E * sizeof(int);

  dim3 blk256(256);
  const int nzero4 = (Ndst + 64 + 3) / 4;
  const int zblocks = (nzero4 + 255) / 256;
  init_kernel<<<32 + zblocks, blk256, 0, stream>>>(Wq, Wk, Wv, Wo, Wb, counts, nzero4);

  const int e4blocks = (E / 4 + 255) / 256;
  qkv_count_kernel<<<e4blocks + NB_KV + NB_Q, blk256, 0, stream>>>(
      x_src, x_dst, Wb, bq, bk, bv, qb, kvb, Nsrc, Ndst, ei, E, counts, e4blocks);

  const int nb = (Ndst + 255) / 256;
  scan_fused_kernel<<<nb, blk256, 0, stream>>>(counts, Ndst, bsums, done, offsets);

  scatter_kernel<<<e4blocks, blk256, 0, stream>>>(ei, E, offsets, csr_src);

  const int ablocks = (Ndst + 3) / 4;
  edge_attn_kernel<<<ablocks, blk256, 0, stream>>>(qb, kvb, eb, offsets, counts,
                                                   csr_src, aggb, Ndst);

  out_gemm_kernel<<<NB_O, blk256, 0, stream>>>(aggb, Wb + 49152, bo, (float*)d_out, Ndst);
}